// Round 2
// baseline (1724.692 us; speedup 1.0000x reference)
//
#include <hip/hip_runtime.h>

// Problem constants (from reference)
constexpr int CB   = 128;   // batch
constexpr int CC   = 12;    // channels
constexpr int CL   = 2048;  // length
constexpr int CK   = 8;     // kernels per group
constexpr int CG   = 32;    // _G = G/2
constexpr int CNCP = 6;     // channels summed per group
constexpr int CND  = 8;     // dilations
constexpr int HALO = 512;   // max tap reach = 4*128
constexpr int BUF  = HALO + CL + HALO + 16; // padded LDS row

// ---------------------------------------------------------------------------
// Transpose W [pair][g*8+k][9] -> Wt [pair][g][j*8+k] so block-uniform weight
// reads become wide scalar loads.
// ---------------------------------------------------------------------------
__global__ void transposeW(const float* __restrict__ W, float* __restrict__ Wt) {
    int t = blockIdx.x * blockDim.x + threadIdx.x;
    constexpr int total = CND * 2 * CG * CK * 9; // 36864
    if (t >= total) return;
    int j = t % 9; int r = t / 9;
    int k = r % CK; r /= CK;
    int g = r % CG; int pair = r / CG;
    Wt[(pair * CG + g) * 72 + j * 8 + k] =
        W[((pair * (CG * CK)) + g * CK + k) * 9 + j];
}

// ---------------------------------------------------------------------------
// Stage: zero halos + hist, build summed row S[l] = sum of 6 gathered
// channels, optionally replace with diff (lane-consecutive => conflict-free).
// ---------------------------------------------------------------------------
__device__ __forceinline__ void stage_row(const float* __restrict__ Xb,
                                          const int* __restrict__ Ig,
                                          int diffi, float* inp, float* hist)
{
    const int tid = threadIdx.x;
    const int c0 = Ig[0], c1 = Ig[1], c2 = Ig[2],
              c3 = Ig[3], c4 = Ig[4], c5 = Ig[5];

    #pragma unroll
    for (int i = tid; i < HALO; i += 256) inp[i] = 0.f;
    for (int i = HALO + CL + tid; i < BUF; i += 256) inp[i] = 0.f;
    if (tid < 16) hist[tid] = 0.f;

    #pragma unroll
    for (int cc = 0; cc < 2; ++cc) {
        const int pos = (tid + cc * 256) * 4;
        const float4 a0 = *(const float4*)(Xb + c0 * CL + pos);
        const float4 a1 = *(const float4*)(Xb + c1 * CL + pos);
        const float4 a2 = *(const float4*)(Xb + c2 * CL + pos);
        const float4 a3 = *(const float4*)(Xb + c3 * CL + pos);
        const float4 a4 = *(const float4*)(Xb + c4 * CL + pos);
        const float4 a5 = *(const float4*)(Xb + c5 * CL + pos);
        float4 s;
        s.x = ((a0.x + a1.x) + (a2.x + a3.x)) + (a4.x + a5.x);
        s.y = ((a0.y + a1.y) + (a2.y + a3.y)) + (a4.y + a5.y);
        s.z = ((a0.z + a1.z) + (a2.z + a3.z)) + (a4.z + a5.z);
        s.w = ((a0.w + a1.w) + (a2.w + a3.w)) + (a4.w + a5.w);
        *(float4*)&inp[HALO + pos] = s;
    }
    __syncthreads();

    if (diffi) {
        // D[l] = S[l+1]-S[l]; lane-consecutive float4 loads (conflict-free).
        float4 f[2], n[2];
        #pragma unroll
        for (int c = 0; c < 2; ++c) {
            const int pos = c * 1024 + tid * 4;
            f[c] = *(const float4*)&inp[HALO + pos];
            n[c] = *(const float4*)&inp[HALO + pos + 4]; // pos+4..7, halo=0 ok
        }
        __syncthreads();
        #pragma unroll
        for (int c = 0; c < 2; ++c) {
            const int pos = c * 1024 + tid * 4;
            float4 d;
            d.x = f[c].y - f[c].x;
            d.y = f[c].z - f[c].y;
            d.z = f[c].w - f[c].z;
            d.w = n[c].x - f[c].w;
            *(float4*)&inp[HALO + pos] = d;
        }
        if (tid == 255) inp[HALO + 2047] = 0.f; // pos 2047 is padding (Lout=2047)
        __syncthreads();
    }
}

// Tournament max/argmax + argmin over 8 values; strict compares keep the
// first occurrence on ties (matches jnp.argmax/argmin).
__device__ __forceinline__ void select8(const float v[8], float& mx, int& mi, int& ni)
{
    float a0 = v[0], a1 = v[2], a2 = v[4], a3 = v[6];
    int   i0 = 0,    i1 = 2,    i2 = 4,    i3 = 6;
    if (v[1] > a0) { a0 = v[1]; i0 = 1; }
    if (v[3] > a1) { a1 = v[3]; i1 = 3; }
    if (v[5] > a2) { a2 = v[5]; i2 = 5; }
    if (v[7] > a3) { a3 = v[7]; i3 = 7; }
    if (a1 > a0) { a0 = a1; i0 = i1; }
    if (a3 > a2) { a2 = a3; i2 = i3; }
    if (a2 > a0) { a0 = a2; i0 = i2; }
    mx = a0; mi = i0;
    float b0 = v[0], b1 = v[2], b2 = v[4], b3 = v[6];
    int   j0 = 0,    j1 = 2,    j2 = 4,    j3 = 6;
    if (v[1] < b0) { b0 = v[1]; j0 = 1; }
    if (v[3] < b1) { b1 = v[3]; j1 = 3; }
    if (v[5] < b2) { b2 = v[5]; j2 = 5; }
    if (v[7] < b3) { b3 = v[7]; j3 = 7; }
    if (b1 < b0) { b0 = b1; j0 = j1; }
    if (b3 < b2) { b2 = b3; j2 = j3; }
    if (b2 < b0) { b0 = b2; j0 = j2; }
    ni = j0;
}

__device__ __forceinline__ void epilogue(float* hist, float* __restrict__ out,
                                         int b, int pair, int g)
{
    __syncthreads();
    const int tid = threadIdx.x;
    if (tid < 16) {
        const int which = tid >> 3, k = tid & 7;
        out[(size_t)b * 8192 + ((pair * 2 + which) * CG + g) * CK + k] = hist[tid];
    }
}

// ---------------------------------------------------------------------------
// Kernel A: runtime dilation D in {4,8,...,128} (D%4==0 -> aligned float4
// taps). ONE code path for 75% of all blocks -> I$ resident.
// ---------------------------------------------------------------------------
__global__ void __launch_bounds__(256)
hydra_big(const float* __restrict__ X, const float* __restrict__ Wt,
          const int* __restrict__ I, float* __restrict__ out)
{
    __shared__ float inp[BUF];
    __shared__ float hist[16];
    const int blk = blockIdx.x;
    const int g = blk & 31;
    int r = blk >> 5;
    const int diffi = r & 1; r >>= 1;          // r = b*6 + (di-2)
    const int di = 2 + (r % 6);
    const int b = r / 6;
    const int pair = di * 2 + diffi;
    const int D = 1 << di;                     // 4..128, uniform per block
    const int tid = threadIdx.x;

    stage_row(X + (size_t)b * (CC * CL), I + (pair * CG + g) * CNCP, diffi, inp, hist);

    const float* __restrict__ Wg = Wt + (pair * CG + g) * 72;
    const int Lout = CL - diffi;

    int tap[9];
    #pragma unroll
    for (int j = 0; j < 9; ++j) tap[j] = HALO + tid * 4 + (j - 4) * D;

    #pragma unroll
    for (int pass = 0; pass < 2; ++pass) {
        const int l0 = pass * 1024 + tid * 4;
        float acc[8][4];
        #pragma unroll
        for (int k = 0; k < 8; ++k)
            #pragma unroll
            for (int p = 0; p < 4; ++p) acc[k][p] = 0.f;

        #pragma unroll
        for (int j = 0; j < 9; ++j) {
            const float4 t = *(const float4*)&inp[tap[j] + pass * 1024];
            const float tv[4] = {t.x, t.y, t.z, t.w};
            #pragma unroll
            for (int k = 0; k < 8; ++k) {
                const float wk = Wg[j * 8 + k];
                #pragma unroll
                for (int p = 0; p < 4; ++p)
                    acc[k][p] = fmaf(wk, tv[p], acc[k][p]);
            }
        }

        #pragma unroll
        for (int p = 0; p < 4; ++p) {
            float v[8];
            #pragma unroll
            for (int k = 0; k < 8; ++k) v[k] = acc[k][p];
            float mx; int mi, ni;
            select8(v, mx, mi, ni);
            if (l0 + p < Lout) {
                unsafeAtomicAdd(&hist[mi], mx);
                unsafeAtomicAdd(&hist[8 + ni], 1.0f);
            }
        }
    }
    epilogue(hist, out, b, pair, g);
}

// ---------------------------------------------------------------------------
// Kernel B: D = 1 or 2 (templated), sliding-window register taps. Each
// instance is its own (small) dispatch -> one code path resident at a time.
// ---------------------------------------------------------------------------
template <int DI>
__global__ void __launch_bounds__(256)
hydra_small(const float* __restrict__ X, const float* __restrict__ Wt,
            const int* __restrict__ I, float* __restrict__ out)
{
    constexpr int D = 1 << DI; // 1 or 2
    __shared__ float inp[BUF];
    __shared__ float hist[16];
    const int blk = blockIdx.x;
    const int g = blk & 31;
    const int diffi = (blk >> 5) & 1;
    const int b = blk >> 6;
    const int pair = DI * 2 + diffi;
    const int tid = threadIdx.x;

    stage_row(X + (size_t)b * (CC * CL), I + (pair * CG + g) * CNCP, diffi, inp, hist);

    const float* __restrict__ Wg = Wt + (pair * CG + g) * 72;
    const int Lout = CL - diffi;

    #pragma unroll
    for (int pass = 0; pass < 2; ++pass) {
        const int l0 = pass * 1024 + tid * 4;
        float acc[8][4];
        #pragma unroll
        for (int k = 0; k < 8; ++k)
            #pragma unroll
            for (int p = 0; p < 4; ++p) acc[k][p] = 0.f;

        constexpr int WN = (D == 1) ? 12 : 20;
        float w[WN];
        const float* base = &inp[HALO + l0 - 4 * D]; // 16B aligned for D=1,2
        #pragma unroll
        for (int i = 0; i < WN / 4; ++i) {
            const float4 t = *(const float4*)(base + i * 4);
            w[4 * i + 0] = t.x; w[4 * i + 1] = t.y;
            w[4 * i + 2] = t.z; w[4 * i + 3] = t.w;
        }
        #pragma unroll
        for (int j = 0; j < 9; ++j) {
            #pragma unroll
            for (int k = 0; k < 8; ++k) {
                const float wk = Wg[j * 8 + k];
                #pragma unroll
                for (int p = 0; p < 4; ++p)
                    acc[k][p] = fmaf(wk, w[p + j * D], acc[k][p]);
            }
        }

        #pragma unroll
        for (int p = 0; p < 4; ++p) {
            float v[8];
            #pragma unroll
            for (int k = 0; k < 8; ++k) v[k] = acc[k][p];
            float mx; int mi, ni;
            select8(v, mx, mi, ni);
            if (l0 + p < Lout) {
                unsafeAtomicAdd(&hist[mi], mx);
                unsafeAtomicAdd(&hist[8 + ni], 1.0f);
            }
        }
    }
    epilogue(hist, out, b, pair, g);
}

extern "C" void kernel_launch(void* const* d_in, const int* in_sizes, int n_in,
                              void* d_out, int out_size, void* d_ws, size_t ws_size,
                              hipStream_t stream)
{
    const float* X = (const float*)d_in[0];
    const float* W = (const float*)d_in[1];
    const int*   I = (const int*)d_in[2];
    float* out = (float*)d_out;
    float* Wt  = (float*)d_ws; // 36864 floats = 144 KiB scratch

    transposeW<<<dim3((36864 + 255) / 256), dim3(256), 0, stream>>>(W, Wt);

    // d in {4..128}: 128 b * 6 di * 2 diff * 32 g = 49152 blocks, one code path
    hydra_big<<<dim3(CB * 6 * 2 * CG), dim3(256), 0, stream>>>(X, Wt, I, out);
    // d = 1 and d = 2: separate small dispatches (one code path each)
    hydra_small<0><<<dim3(CB * 2 * CG), dim3(256), 0, stream>>>(X, Wt, I, out);
    hydra_small<1><<<dim3(CB * 2 * CG), dim3(256), 0, stream>>>(X, Wt, I, out);
}

// Round 3
// 1717.212 us; speedup vs baseline: 1.0044x; 1.0044x over previous
//
#include <hip/hip_runtime.h>

// Problem constants (from reference)
constexpr int CB   = 128;   // batch
constexpr int CC   = 12;    // channels
constexpr int CL   = 2048;  // length
constexpr int CK   = 8;     // kernels per group
constexpr int CG   = 32;    // _G = G/2
constexpr int CNCP = 6;     // channels summed per group
constexpr int CND  = 8;     // dilations
constexpr int HALO = 512;   // max tap reach = 4*128
constexpr int BUF  = HALO + CL + HALO + 16; // padded LDS row

// ---------------------------------------------------------------------------
// Transpose W [pair][g*8+k][9] -> Wt [pair][g][j*8+k] so block-uniform weight
// reads become wide scalar loads.
// ---------------------------------------------------------------------------
__global__ void transposeW(const float* __restrict__ W, float* __restrict__ Wt) {
    int t = blockIdx.x * blockDim.x + threadIdx.x;
    constexpr int total = CND * 2 * CG * CK * 9; // 36864
    if (t >= total) return;
    int j = t % 9; int r = t / 9;
    int k = r % CK; r /= CK;
    int g = r % CG; int pair = r / CG;
    Wt[(pair * CG + g) * 72 + j * 8 + k] =
        W[((pair * (CG * CK)) + g * CK + k) * 9 + j];
}

// ---------------------------------------------------------------------------
// Stage: zero halos + hist, build summed row S[l] = sum of 6 gathered
// channels, optionally replace with diff (lane-consecutive => conflict-free).
// ---------------------------------------------------------------------------
__device__ __forceinline__ void stage_row(const float* __restrict__ Xb,
                                          const int* __restrict__ Ig,
                                          int diffi, float* inp, float* hist)
{
    const int tid = threadIdx.x;
    const int c0 = Ig[0], c1 = Ig[1], c2 = Ig[2],
              c3 = Ig[3], c4 = Ig[4], c5 = Ig[5];

    #pragma unroll
    for (int i = tid; i < HALO; i += 256) inp[i] = 0.f;
    for (int i = HALO + CL + tid; i < BUF; i += 256) inp[i] = 0.f;
    if (tid < 16) hist[tid] = 0.f;

    #pragma unroll
    for (int cc = 0; cc < 2; ++cc) {
        const int pos = (tid + cc * 256) * 4;
        const float4 a0 = *(const float4*)(Xb + c0 * CL + pos);
        const float4 a1 = *(const float4*)(Xb + c1 * CL + pos);
        const float4 a2 = *(const float4*)(Xb + c2 * CL + pos);
        const float4 a3 = *(const float4*)(Xb + c3 * CL + pos);
        const float4 a4 = *(const float4*)(Xb + c4 * CL + pos);
        const float4 a5 = *(const float4*)(Xb + c5 * CL + pos);
        float4 s;
        s.x = ((a0.x + a1.x) + (a2.x + a3.x)) + (a4.x + a5.x);
        s.y = ((a0.y + a1.y) + (a2.y + a3.y)) + (a4.y + a5.y);
        s.z = ((a0.z + a1.z) + (a2.z + a3.z)) + (a4.z + a5.z);
        s.w = ((a0.w + a1.w) + (a2.w + a3.w)) + (a4.w + a5.w);
        *(float4*)&inp[HALO + pos] = s;
    }
    __syncthreads();

    if (diffi) {
        // D[l] = S[l+1]-S[l]; lane-consecutive float4 loads (conflict-free).
        float4 f[2], n[2];
        #pragma unroll
        for (int c = 0; c < 2; ++c) {
            const int pos = c * 1024 + tid * 4;
            f[c] = *(const float4*)&inp[HALO + pos];
            n[c] = *(const float4*)&inp[HALO + pos + 4]; // pos+4..7, halo=0 ok
        }
        __syncthreads();
        #pragma unroll
        for (int c = 0; c < 2; ++c) {
            const int pos = c * 1024 + tid * 4;
            float4 d;
            d.x = f[c].y - f[c].x;
            d.y = f[c].z - f[c].y;
            d.z = f[c].w - f[c].z;
            d.w = n[c].x - f[c].w;
            *(float4*)&inp[HALO + pos] = d;
        }
        if (tid == 255) inp[HALO + 2047] = 0.f; // pos 2047 is padding (Lout=2047)
        __syncthreads();
    }
}

// Tournament max/argmax + argmin over 8 values; strict compares keep the
// first occurrence on ties (matches jnp.argmax/argmin).
__device__ __forceinline__ void select8(const float v[8], float& mx, int& mi, int& ni)
{
    float a0 = v[0], a1 = v[2], a2 = v[4], a3 = v[6];
    int   i0 = 0,    i1 = 2,    i2 = 4,    i3 = 6;
    if (v[1] > a0) { a0 = v[1]; i0 = 1; }
    if (v[3] > a1) { a1 = v[3]; i1 = 3; }
    if (v[5] > a2) { a2 = v[5]; i2 = 5; }
    if (v[7] > a3) { a3 = v[7]; i3 = 7; }
    if (a1 > a0) { a0 = a1; i0 = i1; }
    if (a3 > a2) { a2 = a3; i2 = i3; }
    if (a2 > a0) { a0 = a2; i0 = i2; }
    mx = a0; mi = i0;
    float b0 = v[0], b1 = v[2], b2 = v[4], b3 = v[6];
    int   j0 = 0,    j1 = 2,    j2 = 4,    j3 = 6;
    if (v[1] < b0) { b0 = v[1]; j0 = 1; }
    if (v[3] < b1) { b1 = v[3]; j1 = 3; }
    if (v[5] < b2) { b2 = v[5]; j2 = 5; }
    if (v[7] < b3) { b3 = v[7]; j3 = 7; }
    if (b1 < b0) { b0 = b1; j0 = j1; }
    if (b3 < b2) { b2 = b3; j2 = j3; }
    if (b2 < b0) { b0 = b2; j0 = j2; }
    ni = j0;
}

__device__ __forceinline__ void epilogue(float* hist, float* __restrict__ out,
                                         int b, int pair, int g)
{
    __syncthreads();
    const int tid = threadIdx.x;
    if (tid < 16) {
        const int which = tid >> 3, k = tid & 7;
        out[(size_t)b * 8192 + ((pair * 2 + which) * CG + g) * CK + k] = hist[tid];
    }
}

// ---------------------------------------------------------------------------
// Kernel A: runtime dilation D in {4,8,...,128} (D%4==0 -> aligned float4
// taps). __launch_bounds__(256,4): min 4 waves/EU -> VGPR cap 128, enough
// for acc[8][4]+taps without scratch spills (R2's VGPR_Count=32 => spilling).
// ---------------------------------------------------------------------------
__global__ void __launch_bounds__(256, 4)
hydra_big(const float* __restrict__ X, const float* __restrict__ Wt,
          const int* __restrict__ I, float* __restrict__ out)
{
    __shared__ float inp[BUF];
    __shared__ float hist[16];
    const int blk = blockIdx.x;
    const int g = blk & 31;
    int r = blk >> 5;
    const int diffi = r & 1; r >>= 1;          // r = b*6 + (di-2)
    const int di = 2 + (r % 6);
    const int b = r / 6;
    const int pair = di * 2 + diffi;
    const int D = 1 << di;                     // 4..128, uniform per block
    const int tid = threadIdx.x;

    stage_row(X + (size_t)b * (CC * CL), I + (pair * CG + g) * CNCP, diffi, inp, hist);

    const float* __restrict__ Wg = Wt + (pair * CG + g) * 72;
    const int Lout = CL - diffi;

    #pragma unroll
    for (int pass = 0; pass < 2; ++pass) {
        const int l0 = pass * 1024 + tid * 4;
        float acc[8][4];
        #pragma unroll
        for (int k = 0; k < 8; ++k)
            #pragma unroll
            for (int p = 0; p < 4; ++p) acc[k][p] = 0.f;

        #pragma unroll
        for (int j = 0; j < 9; ++j) {
            const float4 t = *(const float4*)&inp[HALO + l0 + (j - 4) * D];
            const float tv[4] = {t.x, t.y, t.z, t.w};
            #pragma unroll
            for (int k = 0; k < 8; ++k) {
                const float wk = Wg[j * 8 + k];
                #pragma unroll
                for (int p = 0; p < 4; ++p)
                    acc[k][p] = fmaf(wk, tv[p], acc[k][p]);
            }
        }

        #pragma unroll
        for (int p = 0; p < 4; ++p) {
            float v[8];
            #pragma unroll
            for (int k = 0; k < 8; ++k) v[k] = acc[k][p];
            float mx; int mi, ni;
            select8(v, mx, mi, ni);
            if (l0 + p < Lout) {
                unsafeAtomicAdd(&hist[mi], mx);
                unsafeAtomicAdd(&hist[8 + ni], 1.0f);
            }
        }
    }
    epilogue(hist, out, b, pair, g);
}

// ---------------------------------------------------------------------------
// Kernel B: D = 1 or 2 (templated), sliding-window register taps.
// ---------------------------------------------------------------------------
template <int DI>
__global__ void __launch_bounds__(256, 4)
hydra_small(const float* __restrict__ X, const float* __restrict__ Wt,
            const int* __restrict__ I, float* __restrict__ out)
{
    constexpr int D = 1 << DI; // 1 or 2
    __shared__ float inp[BUF];
    __shared__ float hist[16];
    const int blk = blockIdx.x;
    const int g = blk & 31;
    const int diffi = (blk >> 5) & 1;
    const int b = blk >> 6;
    const int pair = DI * 2 + diffi;
    const int tid = threadIdx.x;

    stage_row(X + (size_t)b * (CC * CL), I + (pair * CG + g) * CNCP, diffi, inp, hist);

    const float* __restrict__ Wg = Wt + (pair * CG + g) * 72;
    const int Lout = CL - diffi;

    #pragma unroll
    for (int pass = 0; pass < 2; ++pass) {
        const int l0 = pass * 1024 + tid * 4;
        float acc[8][4];
        #pragma unroll
        for (int k = 0; k < 8; ++k)
            #pragma unroll
            for (int p = 0; p < 4; ++p) acc[k][p] = 0.f;

        constexpr int WN = (D == 1) ? 12 : 20;
        float w[WN];
        const float* base = &inp[HALO + l0 - 4 * D]; // 16B aligned for D=1,2
        #pragma unroll
        for (int i = 0; i < WN / 4; ++i) {
            const float4 t = *(const float4*)(base + i * 4);
            w[4 * i + 0] = t.x; w[4 * i + 1] = t.y;
            w[4 * i + 2] = t.z; w[4 * i + 3] = t.w;
        }
        #pragma unroll
        for (int j = 0; j < 9; ++j) {
            #pragma unroll
            for (int k = 0; k < 8; ++k) {
                const float wk = Wg[j * 8 + k];
                #pragma unroll
                for (int p = 0; p < 4; ++p)
                    acc[k][p] = fmaf(wk, w[p + j * D], acc[k][p]);
            }
        }

        #pragma unroll
        for (int p = 0; p < 4; ++p) {
            float v[8];
            #pragma unroll
            for (int k = 0; k < 8; ++k) v[k] = acc[k][p];
            float mx; int mi, ni;
            select8(v, mx, mi, ni);
            if (l0 + p < Lout) {
                unsafeAtomicAdd(&hist[mi], mx);
                unsafeAtomicAdd(&hist[8 + ni], 1.0f);
            }
        }
    }
    epilogue(hist, out, b, pair, g);
}

extern "C" void kernel_launch(void* const* d_in, const int* in_sizes, int n_in,
                              void* d_out, int out_size, void* d_ws, size_t ws_size,
                              hipStream_t stream)
{
    const float* X = (const float*)d_in[0];
    const float* W = (const float*)d_in[1];
    const int*   I = (const int*)d_in[2];
    float* out = (float*)d_out;
    float* Wt  = (float*)d_ws; // 36864 floats = 144 KiB scratch

    transposeW<<<dim3((36864 + 255) / 256), dim3(256), 0, stream>>>(W, Wt);

    // d in {4..128}: 128 b * 6 di * 2 diff * 32 g = 49152 blocks, one code path
    hydra_big<<<dim3(CB * 6 * 2 * CG), dim3(256), 0, stream>>>(X, Wt, I, out);
    // d = 1 and d = 2: separate small dispatches (one code path each)
    hydra_small<0><<<dim3(CB * 2 * CG), dim3(256), 0, stream>>>(X, Wt, I, out);
    hydra_small<1><<<dim3(CB * 2 * CG), dim3(256), 0, stream>>>(X, Wt, I, out);
}